// Round 1
// 529.965 us; speedup vs baseline: 1.0149x; 1.0149x over previous
//
#include <hip/hip_runtime.h>

// Pair feature expansion: out[i*512+j] = concat(x_i[0:260], x_j[0:260], r1, r2)
// n=512, d=260, out row = 522 floats (2088 B). Output 547 MB -> pure write-bound.
//
// R3 insight: the 16 rows a block produces (fixed i, j-tile) are one CONTIGUOUS
// 16B-aligned region of 16*2088 = 33408 B (row index i*512+j0 is even, and
// 2*2088 is a multiple of 16). So build the full 16-row image in LDS (phase A,
// all global loads happen here), then phase B is a pure aligned float4 stream:
// contiguous ds_read_b128 -> contiguous global_store_dwordx4 -- byte-identical
// in shape to fillBufferAligned, which measures 6.27 TB/s on this buffer.
// No global load is ever issued after the first store (vmcnt FIFO stays
// store-only), no misaligned 8B bursts, no 5-lane tail stores.
//
// LDS image layout per row (float2 slots, 261 per row):
//   slot 0..63    = x_i[0:128]     (regs xi_a)
//   slot 64..127  = x_i[128:256]   (regs xi_b)
//   slot 128..129 = x_i bbox       (regs bb)
//   slot 130..193 = x_j[0:128]     (global, L2-resident)
//   slot 194..257 = x_j[128:256]   (global)
//   slot 258..259 = x_j bbox       (global)
//   slot 260      = (r1, r2)       (computed by lane 2)
//
// LDS = 33.4 KB -> 4 blocks/CU, 16 waves/CU.

#define N 512
#define D 260
#define JT 16
#define ROW 522
#define REG_F4 (JT * ROW / 4)   // 2088 float4 per block region

__global__ __launch_bounds__(256) void pair_kernel(const float* __restrict__ in,
                                                   float* __restrict__ out) {
    const int b    = blockIdx.x;
    const int i    = b >> 5;            // 32 j-tiles per i
    const int j0   = (b & 31) * JT;
    const int tid  = threadIdx.x;
    const int lane = tid & 63;
    const int w    = tid >> 6;

    __shared__ __align__(16) float s_img[JT * ROW];

    // x_i sources live in registers (broadcast row, L2-resident).
    const float* rowi = in + i * D;
    const float2 xi_a = ((const float2*)rowi)[lane];        // x_i[2l..2l+1]
    const float2 xi_b = ((const float2*)rowi)[64 + lane];   // x_i[128+2l..]
    const float4 bb   = *(const float4*)(rowi + 256);       // x_i bbox

    // ---- Phase A: build the 16-row image in LDS. All global loads here. ----
    for (int lj = w; lj < JT; lj += 4) {
        const float* xjrow = in + (size_t)(j0 + lj) * D;
        const float2 ga = ((const float2*)xjrow)[lane];        // x_j[2l..2l+1]
        const float2 gb = ((const float2*)xjrow)[64 + lane];   // x_j[128+2l..]
        float2* row2 = (float2*)(s_img + lj * ROW);            // 8B-aligned

        row2[lane]       = xi_a;
        row2[64 + lane]  = xi_b;
        row2[130 + lane] = ga;
        row2[194 + lane] = gb;
        if (lane < 2) {
            row2[128 + lane] = lane ? make_float2(bb.z, bb.w)
                                    : make_float2(bb.x, bb.y);
            row2[258 + lane] = ((const float2*)xjrow)[128 + lane];  // x_j bbox
        }
        if (lane == 2) {
            const float4 bj = *(const float4*)(xjrow + 256);
            const float ww = fmaxf(0.0f, fminf(bb.z, bj.z) - fmaxf(bb.x, bj.x));
            const float hh = fmaxf(0.0f, fminf(bb.w, bj.w) - fmaxf(bb.y, bj.y));
            const float inter = ww * hh;
            row2[260] = make_float2(inter / ((bb.z - bb.x) * (bb.w - bb.y)),
                                    inter / ((bj.z - bj.x) * (bj.w - bj.y)));
        }
    }
    __syncthreads();

    // ---- Phase B: pure aligned float4 store stream (fill-kernel shape). ----
    const float4* s4 = (const float4*)s_img;
    float4* o4 = (float4*)(out + (size_t)(i * N + j0) * ROW);  // 16B-aligned

    int t = tid;
    #pragma unroll
    for (int k = 0; k < 8; ++k, t += 256) {   // 8 * 256 = 2048 float4
        o4[t] = s4[t];
    }
    if (t < REG_F4) o4[t] = s4[t];            // tail: 40 float4 (tid < 40)
}

extern "C" void kernel_launch(void* const* d_in, const int* in_sizes, int n_in,
                              void* d_out, int out_size, void* d_ws, size_t ws_size,
                              hipStream_t stream) {
    const float* in = (const float*)d_in[0];
    float* out = (float*)d_out;
    pair_kernel<<<N * (N / JT), 256, 0, stream>>>(in, out);
}